// Round 5
// baseline (929.954 us; speedup 1.0000x reference)
//
#include <hip/hip_runtime.h>
#include <math.h>

#define BIGF 3.0e38f

// ---------------------------------------------------------------------------
// top-3 insert, ascending d, strict < so earliest index wins ties (matches
// stable lax.top_k tie-breaking when scanning sources in ascending order)
// ---------------------------------------------------------------------------
__device__ __forceinline__ void top3_insert(float d, int idx,
                                            float& d0, float& d1, float& d2,
                                            int& i0, int& i1, int& i2) {
  if (d < d2) {
    if (d < d1) {
      d2 = d1; i2 = i1;
      if (d < d0) { d1 = d0; i1 = i0; d0 = d; i0 = idx; }
      else        { d1 = d;  i1 = idx; }
    } else { d2 = d; i2 = idx; }
  }
}

// ---------------------------------------------------------------------------
// Phase 1: per (query, source-chunk) local top-3 of the REFERENCE's fp32
// expansion distance, evaluated with NO fma contraction anywhere:
//   sx  = (x*x + y*y) + z*z          (sequential, individually rounded)
//   dot = (p0 + p1) + p2,  p_k = q_k*s_k  (individually rounded)
//   d2  = (sy + sx) - 2*dot          (2*dot exact)
// #pragma clang fp contract(off) guarantees hipcc (-ffp-contract=fast by
// default) cannot fuse these into fmas — rounds 3/4 were silently contracted.
// ---------------------------------------------------------------------------
__global__ __launch_bounds__(256) void knn_part_kernel(
    const float* __restrict__ qpos, int Nq,
    const float* __restrict__ spos, int Ns,
    int chunkSize,
    float* __restrict__ part_d, int* __restrict__ part_i)
{
  #pragma clang fp contract(off)
  __shared__ float4 s_src[2048];
  const int tid = threadIdx.x;
  const int chunk = blockIdx.y;
  const int s0 = chunk * chunkSize;
  const int count = min(chunkSize, Ns - s0);

  for (int i = tid; i < count; i += 256) {
    const float* p = &spos[(size_t)(s0 + i) * 3];
    float x = p[0], y = p[1], z = p[2];
    float sx = (x * x + y * y) + z * z;   // sequential, no contraction
    s_src[i] = make_float4(x, y, z, sx);
  }
  __syncthreads();

  const int q = blockIdx.x * 256 + tid;
  if (q >= Nq) return;
  const float* qp = &qpos[(size_t)q * 3];
  const float qx = qp[0], qy = qp[1], qz = qp[2];
  const float sy = (qx * qx + qy * qy) + qz * qz;  // sequential, no contraction

  float d0 = BIGF, d1 = BIGF, d2 = BIGF;
  int i0 = -1, i1 = -1, i2 = -1;

  #pragma unroll 4
  for (int i = 0; i < count; ++i) {
    float4 s = s_src[i];
    float p0 = qx * s.x;
    float p1 = qy * s.y;
    float p2 = qz * s.z;
    float dot = (p0 + p1) + p2;          // non-fma, ascending k
    float S = sy + s.w;                  // rnd(sy + sx)
    float d = S - 2.0f * dot;            // 2*dot exact, subtract rounded
    top3_insert(d, s0 + i, d0, d1, d2, i0, i1, i2);
  }

  size_t base = ((size_t)chunk * (size_t)Nq + (size_t)q) * 3;
  part_d[base + 0] = d0; part_d[base + 1] = d1; part_d[base + 2] = d2;
  part_i[base + 0] = i0; part_i[base + 1] = i1; part_i[base + 2] = i2;
}

// ---------------------------------------------------------------------------
// Phase 2: merge chunk-local top-3s, build normalized inverse-d2 weights.
// part_d holds the reference-replicated expansion d2 (may be <= 0 -> clip).
// mode 0: write w[Nq,3], idx[Nq,3]
// mode 1: out3 = base3 - sum_k w_k * feat3[idx_k]   (F = 3)
// mode 2: out3 =          sum_k w_k * feat3[idx_k]
// ---------------------------------------------------------------------------
__global__ __launch_bounds__(256) void knn_merge_kernel(
    int Nq, int nchunk,
    const float* __restrict__ part_d, const int* __restrict__ part_i,
    int mode,
    const float* __restrict__ base3,
    const float* __restrict__ feat3,
    float* __restrict__ w_out, int* __restrict__ i_out,
    float* __restrict__ out3)
{
  const int q = blockIdx.x * 256 + threadIdx.x;
  if (q >= Nq) return;

  float d0 = BIGF, d1 = BIGF, d2 = BIGF;
  int i0 = -1, i1 = -1, i2 = -1;
  for (int c = 0; c < nchunk; ++c) {
    size_t base = ((size_t)c * (size_t)Nq + (size_t)q) * 3;
    #pragma unroll
    for (int k = 0; k < 3; ++k)
      top3_insert(part_d[base + k], part_i[base + k], d0, d1, d2, i0, i1, i2);
  }

  float w0 = 1.0f / fmaxf(d0, 1e-16f);
  float w1 = 1.0f / fmaxf(d1, 1e-16f);
  float w2 = 1.0f / fmaxf(d2, 1e-16f);
  float inv = 1.0f / (w0 + w1 + w2);
  w0 *= inv; w1 *= inv; w2 *= inv;

  if (mode == 0) {
    w_out[(size_t)q * 3 + 0] = w0; w_out[(size_t)q * 3 + 1] = w1; w_out[(size_t)q * 3 + 2] = w2;
    i_out[(size_t)q * 3 + 0] = i0; i_out[(size_t)q * 3 + 1] = i1; i_out[(size_t)q * 3 + 2] = i2;
  } else {
    #pragma unroll
    for (int f = 0; f < 3; ++f) {
      float v = w0 * feat3[(size_t)i0 * 3 + f]
              + w1 * feat3[(size_t)i1 * 3 + f]
              + w2 * feat3[(size_t)i2 * 3 + f];
      out3[(size_t)q * 3 + f] = (mode == 1) ? (base3[(size_t)q * 3 + f] - v) : v;
    }
  }
}

// ---------------------------------------------------------------------------
// t[q, :] = emb1[q, :] - sum_k w_k * emb2[idx_k, :]     (F = 256, float4)
// ---------------------------------------------------------------------------
__global__ __launch_bounds__(256) void build_t_kernel(
    const float* __restrict__ emb1, const float* __restrict__ emb2,
    const float* __restrict__ w, const int* __restrict__ idx,
    float* __restrict__ t, int Nq)
{
  int gid = blockIdx.x * 256 + threadIdx.x;   // Nq*64 threads, 64 float4 per row
  int q = gid >> 6, c4 = gid & 63;
  if (q >= Nq) return;
  float w0 = w[(size_t)q * 3 + 0], w1 = w[(size_t)q * 3 + 1], w2 = w[(size_t)q * 3 + 2];
  int i0 = idx[(size_t)q * 3 + 0], i1 = idx[(size_t)q * 3 + 1], i2 = idx[(size_t)q * 3 + 2];
  const float4* e1 = (const float4*)emb1;
  const float4* e2 = (const float4*)emb2;
  float4 a  = e1[(size_t)q * 64 + c4];
  float4 f0 = e2[(size_t)i0 * 64 + c4];
  float4 f1 = e2[(size_t)i1 * 64 + c4];
  float4 f2 = e2[(size_t)i2 * 64 + c4];
  float4 r;
  r.x = a.x - (w0 * f0.x + w1 * f1.x + w2 * f2.x);
  r.y = a.y - (w0 * f0.y + w1 * f1.y + w2 * f2.y);
  r.z = a.z - (w0 * f0.z + w1 * f1.z + w2 * f2.z);
  r.w = a.w - (w0 * f0.w + w1 * f1.w + w2 * f2.w);
  ((float4*)t)[(size_t)q * 64 + c4] = r;
}

// ---------------------------------------------------------------------------
// C = act(A[M,K] @ W[K,N] + b), fp32 vector GEMM.
// 128x128 tile, 256 threads, 8x8 micro-tile, BK=8.
// ---------------------------------------------------------------------------
#define GBM 128
#define GBN 128
#define GBK 8
__global__ __launch_bounds__(256) void gemm_bias_act_kernel(
    const float* __restrict__ A, const float* __restrict__ W,
    const float* __restrict__ bias, float* __restrict__ C,
    int M, int N, int K, int relu)
{
  __shared__ float As[GBK][GBM];
  __shared__ float Bs[GBK][GBN];
  const int tid = threadIdx.x;
  const int row0 = blockIdx.x * GBM;
  const int col0 = blockIdx.y * GBN;
  const int ty = tid >> 4, tx = tid & 15;

  const int arow  = tid >> 1;
  const int acol4 = (tid & 1) * 4;
  const int brow  = tid >> 5;
  const int bcol4 = (tid & 31) * 4;

  float acc[8][8];
  #pragma unroll
  for (int i = 0; i < 8; ++i)
    #pragma unroll
    for (int j = 0; j < 8; ++j) acc[i][j] = 0.0f;

  for (int k0 = 0; k0 < K; k0 += GBK) {
    float4 av = *(const float4*)&A[(size_t)(row0 + arow) * K + k0 + acol4];
    float4 bv = *(const float4*)&W[(size_t)(k0 + brow) * N + col0 + bcol4];
    __syncthreads();
    As[acol4 + 0][arow] = av.x;
    As[acol4 + 1][arow] = av.y;
    As[acol4 + 2][arow] = av.z;
    As[acol4 + 3][arow] = av.w;
    *(float4*)&Bs[brow][bcol4] = bv;
    __syncthreads();
    #pragma unroll
    for (int k = 0; k < GBK; ++k) {
      float a[8], b[8];
      *(float4*)&a[0] = *(const float4*)&As[k][ty * 8 + 0];
      *(float4*)&a[4] = *(const float4*)&As[k][ty * 8 + 4];
      *(float4*)&b[0] = *(const float4*)&Bs[k][tx * 8 + 0];
      *(float4*)&b[4] = *(const float4*)&Bs[k][tx * 8 + 4];
      #pragma unroll
      for (int i = 0; i < 8; ++i)
        #pragma unroll
        for (int j = 0; j < 8; ++j)
          acc[i][j] = fmaf(a[i], b[j], acc[i][j]);
    }
  }

  #pragma unroll
  for (int i = 0; i < 8; ++i) {
    size_t r = (size_t)(row0 + ty * 8 + i);
    #pragma unroll
    for (int j = 0; j < 8; ++j) {
      int c = col0 + tx * 8 + j;
      float v = acc[i][j] + bias[c];
      if (relu) v = fmaxf(v, 0.0f);
      C[r * N + c] = v;
    }
  }
}

// ---------------------------------------------------------------------------
// out[r, :] = h2[r, :] @ W3[256,3] + b3 + res[r, :]   (wave per row)
// ---------------------------------------------------------------------------
__global__ __launch_bounds__(256) void final_kernel(
    const float* __restrict__ h2, const float* __restrict__ W3,
    const float* __restrict__ b3, const float* __restrict__ res,
    float* __restrict__ out, int M)
{
  __shared__ float sW3[768];
  const int tid = threadIdx.x;
  for (int i = tid; i < 768; i += 256) sW3[i] = W3[i];
  __syncthreads();

  const int wave = tid >> 6, lane = tid & 63;
  const int r = blockIdx.x * 4 + wave;
  if (r >= M) return;

  float4 h = ((const float4*)h2)[(size_t)r * 64 + lane];
  const int c = lane * 4;
  float a0 = h.x * sW3[(c + 0) * 3 + 0] + h.y * sW3[(c + 1) * 3 + 0]
           + h.z * sW3[(c + 2) * 3 + 0] + h.w * sW3[(c + 3) * 3 + 0];
  float a1 = h.x * sW3[(c + 0) * 3 + 1] + h.y * sW3[(c + 1) * 3 + 1]
           + h.z * sW3[(c + 2) * 3 + 1] + h.w * sW3[(c + 3) * 3 + 1];
  float a2 = h.x * sW3[(c + 0) * 3 + 2] + h.y * sW3[(c + 1) * 3 + 2]
           + h.z * sW3[(c + 2) * 3 + 2] + h.w * sW3[(c + 3) * 3 + 2];

  #pragma unroll
  for (int off = 32; off; off >>= 1) {
    a0 += __shfl_xor(a0, off);
    a1 += __shfl_xor(a1, off);
    a2 += __shfl_xor(a2, off);
  }
  if (lane == 0) {
    out[(size_t)r * 3 + 0] = a0 + b3[0] + res[(size_t)r * 3 + 0];
    out[(size_t)r * 3 + 1] = a1 + b3[1] + res[(size_t)r * 3 + 1];
    out[(size_t)r * 3 + 2] = a2 + b3[2] + res[(size_t)r * 3 + 2];
  }
}

// ---------------------------------------------------------------------------
extern "C" void kernel_launch(void* const* d_in, const int* in_sizes, int n_in,
                              void* d_out, int out_size, void* d_ws, size_t ws_size,
                              hipStream_t stream) {
  (void)in_sizes; (void)n_in; (void)out_size; (void)ws_size;
  const float* emb1   = (const float*)d_in[0];
  const float* l_y1   = (const float*)d_in[1];
  const float* l_pos1 = (const float*)d_in[2];
  const float* h_pos1 = (const float*)d_in[3];
  const float* emb2   = (const float*)d_in[4];
  const float* l_y2   = (const float*)d_in[5];
  const float* l_pos2 = (const float*)d_in[6];
  const float* h_pos2 = (const float*)d_in[7];
  const float* W1     = (const float*)d_in[8];
  const float* b1     = (const float*)d_in[9];
  const float* W2     = (const float*)d_in[10];
  const float* b2     = (const float*)d_in[11];
  const float* W3     = (const float*)d_in[12];
  const float* b3     = (const float*)d_in[13];
  float* out = (float*)d_out;

  const int Nh = 16384, Nl = 4096, H = 256;

  // workspace layout
  char* ws = (char*)d_ws;
  int*   idxA  = (int*)(ws + 0);                       // 196608 B
  float* wA    = (float*)(ws + 196608);                // 196608 B
  float* tbuf  = (float*)(ws + 393216);                // 16 MB
  float* h1    = (float*)(ws + 393216 + 16777216);     // 16 MB
  float* h2    = tbuf;                                 // reuse t region
  float* diff  = (float*)(ws + 393216 + 2 * 16777216);            // 49152 B
  float* res   = (float*)(ws + 393216 + 2 * 16777216 + 49152);    // 196608 B
  float* partd = (float*)(ws + 393216 + 2 * 16777216 + 49152 + 196608);            // 1.5 MB
  int*   parti = (int*)  (ws + 393216 + 2 * 16777216 + 49152 + 196608 + 1572864);  // 1.5 MB

  // ---- branch 1: x = mlp(emb1 - interp(emb2; h_pos2 -> h_pos1)) ----
  knn_part_kernel<<<dim3(Nh / 256, 8), 256, 0, stream>>>(
      h_pos1, Nh, h_pos2, Nh, 2048, partd, parti);
  knn_merge_kernel<<<dim3(Nh / 256), 256, 0, stream>>>(
      Nh, 8, partd, parti, 0, nullptr, nullptr, wA, idxA, nullptr);
  build_t_kernel<<<dim3(Nh * 64 / 256), 256, 0, stream>>>(
      emb1, emb2, wA, idxA, tbuf, Nh);
  gemm_bias_act_kernel<<<dim3(Nh / GBM, H / GBN), 256, 0, stream>>>(
      tbuf, W1, b1, h1, Nh, H, H, 1);
  gemm_bias_act_kernel<<<dim3(Nh / GBM, H / GBN), 256, 0, stream>>>(
      h1, W2, b2, h2, Nh, H, H, 1);

  // ---- branch 2: res = interp(l_y1 - interp(l_y2; l_pos2->l_pos1); l_pos1->h_pos1) ----
  knn_part_kernel<<<dim3(Nl / 256, 4), 256, 0, stream>>>(
      l_pos1, Nl, l_pos2, Nl, 1024, partd, parti);
  knn_merge_kernel<<<dim3(Nl / 256), 256, 0, stream>>>(
      Nl, 4, partd, parti, 1, l_y1, l_y2, nullptr, nullptr, diff);
  knn_part_kernel<<<dim3(Nh / 256, 4), 256, 0, stream>>>(
      h_pos1, Nh, l_pos1, Nl, 1024, partd, parti);
  knn_merge_kernel<<<dim3(Nh / 256), 256, 0, stream>>>(
      Nh, 4, partd, parti, 2, nullptr, diff, nullptr, nullptr, res);

  // ---- final: out = (h2 @ W3 + b3) + res ----
  final_kernel<<<dim3(Nh / 4), 256, 0, stream>>>(h2, W3, b3, res, out, Nh);
}

// Round 6
// 352.642 us; speedup vs baseline: 2.6371x; 2.6371x over previous
//
#include <hip/hip_runtime.h>
#include <math.h>

#define BIGF 3.0e38f

// ---------------------------------------------------------------------------
// top-3 insert, BRANCHLESS (3 v_cmp + cndmask chain, pipelinable).
// Strict < everywhere: earliest index wins ties — identical semantics to the
// verified round-5 branchy version (do not alter: selection must replicate
// the np reference's fp32 ordering).
// ---------------------------------------------------------------------------
__device__ __forceinline__ void top3_insert(float d, int idx,
                                            float& d0, float& d1, float& d2,
                                            int& i0, int& i1, int& i2) {
  const bool c0 = d < d0, c1 = d < d1, c2 = d < d2;
  float nd0 = c0 ? d   : d0;
  int   ni0 = c0 ? idx : i0;
  float nd1 = c0 ? d0  : (c1 ? d   : d1);
  int   ni1 = c0 ? i0  : (c1 ? idx : i1);
  float nd2 = c1 ? d1  : (c2 ? d   : d2);
  int   ni2 = c1 ? i1  : (c2 ? idx : i2);
  d0 = nd0; d1 = nd1; d2 = nd2;
  i0 = ni0; i1 = ni1; i2 = ni2;
}

// ---------------------------------------------------------------------------
// Phase 1: per (query, source-chunk) local top-3 of the REFERENCE's fp32
// expansion distance, evaluated with NO fma contraction anywhere:
//   sx  = (x*x + y*y) + z*z          (sequential, individually rounded)
//   dot = (p0 + p1) + p2,  p_k = q_k*s_k  (individually rounded)
//   d2  = (sy + sx) - 2*dot          (2*dot exact)
// contract(off) is REQUIRED: hipcc defaults to -ffp-contract=fast and the
// fused version selects different neighbors than the np reference (r3/r4).
// chunkSize <= 512.
// ---------------------------------------------------------------------------
__global__ __launch_bounds__(256) void knn_part_kernel(
    const float* __restrict__ qpos, int Nq,
    const float* __restrict__ spos, int Ns,
    int chunkSize,
    float* __restrict__ part_d, int* __restrict__ part_i)
{
  #pragma clang fp contract(off)
  __shared__ float4 s_src[512];
  const int tid = threadIdx.x;
  const int chunk = blockIdx.y;
  const int s0 = chunk * chunkSize;
  const int count = min(chunkSize, Ns - s0);

  for (int i = tid; i < count; i += 256) {
    const float* p = &spos[(size_t)(s0 + i) * 3];
    float x = p[0], y = p[1], z = p[2];
    float sx = (x * x + y * y) + z * z;   // sequential, no contraction
    s_src[i] = make_float4(x, y, z, sx);
  }
  __syncthreads();

  const int q = blockIdx.x * 256 + tid;
  if (q >= Nq) return;
  const float* qp = &qpos[(size_t)q * 3];
  const float qx = qp[0], qy = qp[1], qz = qp[2];
  const float sy = (qx * qx + qy * qy) + qz * qz;  // sequential, no contraction

  float d0 = BIGF, d1 = BIGF, d2 = BIGF;
  int i0 = -1, i1 = -1, i2 = -1;

  #pragma unroll 8
  for (int i = 0; i < count; ++i) {
    float4 s = s_src[i];
    float p0 = qx * s.x;
    float p1 = qy * s.y;
    float p2 = qz * s.z;
    float dot = (p0 + p1) + p2;          // non-fma, ascending k
    float S = sy + s.w;                  // rnd(sy + sx)
    float d = S - 2.0f * dot;            // 2*dot exact, subtract rounded
    top3_insert(d, s0 + i, d0, d1, d2, i0, i1, i2);
  }

  size_t base = ((size_t)chunk * (size_t)Nq + (size_t)q) * 3;
  part_d[base + 0] = d0; part_d[base + 1] = d1; part_d[base + 2] = d2;
  part_i[base + 0] = i0; part_i[base + 1] = i1; part_i[base + 2] = i2;
}

// ---------------------------------------------------------------------------
// Phase 2: merge chunk-local top-3s (ascending chunk order == ascending
// global index order for tie-break), build normalized inverse-d2 weights.
// mode 0: write w[Nq,3], idx[Nq,3]
// mode 1: out3 = base3 - sum_k w_k * feat3[idx_k]   (F = 3)
// mode 2: out3 =          sum_k w_k * feat3[idx_k]
// ---------------------------------------------------------------------------
__global__ __launch_bounds__(256) void knn_merge_kernel(
    int Nq, int nchunk,
    const float* __restrict__ part_d, const int* __restrict__ part_i,
    int mode,
    const float* __restrict__ base3,
    const float* __restrict__ feat3,
    float* __restrict__ w_out, int* __restrict__ i_out,
    float* __restrict__ out3)
{
  const int q = blockIdx.x * 256 + threadIdx.x;
  if (q >= Nq) return;

  float d0 = BIGF, d1 = BIGF, d2 = BIGF;
  int i0 = -1, i1 = -1, i2 = -1;
  for (int c = 0; c < nchunk; ++c) {
    size_t base = ((size_t)c * (size_t)Nq + (size_t)q) * 3;
    #pragma unroll
    for (int k = 0; k < 3; ++k)
      top3_insert(part_d[base + k], part_i[base + k], d0, d1, d2, i0, i1, i2);
  }

  float w0 = 1.0f / fmaxf(d0, 1e-16f);
  float w1 = 1.0f / fmaxf(d1, 1e-16f);
  float w2 = 1.0f / fmaxf(d2, 1e-16f);
  float inv = 1.0f / (w0 + w1 + w2);
  w0 *= inv; w1 *= inv; w2 *= inv;

  if (mode == 0) {
    w_out[(size_t)q * 3 + 0] = w0; w_out[(size_t)q * 3 + 1] = w1; w_out[(size_t)q * 3 + 2] = w2;
    i_out[(size_t)q * 3 + 0] = i0; i_out[(size_t)q * 3 + 1] = i1; i_out[(size_t)q * 3 + 2] = i2;
  } else {
    #pragma unroll
    for (int f = 0; f < 3; ++f) {
      float v = w0 * feat3[(size_t)i0 * 3 + f]
              + w1 * feat3[(size_t)i1 * 3 + f]
              + w2 * feat3[(size_t)i2 * 3 + f];
      out3[(size_t)q * 3 + f] = (mode == 1) ? (base3[(size_t)q * 3 + f] - v) : v;
    }
  }
}

// ---------------------------------------------------------------------------
// t[q, :] = emb1[q, :] - sum_k w_k * emb2[idx_k, :]     (F = 256, float4)
// ---------------------------------------------------------------------------
__global__ __launch_bounds__(256) void build_t_kernel(
    const float* __restrict__ emb1, const float* __restrict__ emb2,
    const float* __restrict__ w, const int* __restrict__ idx,
    float* __restrict__ t, int Nq)
{
  int gid = blockIdx.x * 256 + threadIdx.x;   // Nq*64 threads, 64 float4 per row
  int q = gid >> 6, c4 = gid & 63;
  if (q >= Nq) return;
  float w0 = w[(size_t)q * 3 + 0], w1 = w[(size_t)q * 3 + 1], w2 = w[(size_t)q * 3 + 2];
  int i0 = idx[(size_t)q * 3 + 0], i1 = idx[(size_t)q * 3 + 1], i2 = idx[(size_t)q * 3 + 2];
  const float4* e1 = (const float4*)emb1;
  const float4* e2 = (const float4*)emb2;
  float4 a  = e1[(size_t)q * 64 + c4];
  float4 f0 = e2[(size_t)i0 * 64 + c4];
  float4 f1 = e2[(size_t)i1 * 64 + c4];
  float4 f2 = e2[(size_t)i2 * 64 + c4];
  float4 r;
  r.x = a.x - (w0 * f0.x + w1 * f1.x + w2 * f2.x);
  r.y = a.y - (w0 * f0.y + w1 * f1.y + w2 * f2.y);
  r.z = a.z - (w0 * f0.z + w1 * f1.z + w2 * f2.z);
  r.w = a.w - (w0 * f0.w + w1 * f1.w + w2 * f2.w);
  ((float4*)t)[(size_t)q * 64 + c4] = r;
}

// ---------------------------------------------------------------------------
// C = act(A[M,K] @ W[K,N] + b), fp32 vector GEMM.
// 128x128 tile, 256 threads, 8x8 micro-tile, BK=8.
// ---------------------------------------------------------------------------
#define GBM 128
#define GBN 128
#define GBK 8
__global__ __launch_bounds__(256) void gemm_bias_act_kernel(
    const float* __restrict__ A, const float* __restrict__ W,
    const float* __restrict__ bias, float* __restrict__ C,
    int M, int N, int K, int relu)
{
  __shared__ float As[GBK][GBM];
  __shared__ float Bs[GBK][GBN];
  const int tid = threadIdx.x;
  const int row0 = blockIdx.x * GBM;
  const int col0 = blockIdx.y * GBN;
  const int ty = tid >> 4, tx = tid & 15;

  const int arow  = tid >> 1;
  const int acol4 = (tid & 1) * 4;
  const int brow  = tid >> 5;
  const int bcol4 = (tid & 31) * 4;

  float acc[8][8];
  #pragma unroll
  for (int i = 0; i < 8; ++i)
    #pragma unroll
    for (int j = 0; j < 8; ++j) acc[i][j] = 0.0f;

  for (int k0 = 0; k0 < K; k0 += GBK) {
    float4 av = *(const float4*)&A[(size_t)(row0 + arow) * K + k0 + acol4];
    float4 bv = *(const float4*)&W[(size_t)(k0 + brow) * N + col0 + bcol4];
    __syncthreads();
    As[acol4 + 0][arow] = av.x;
    As[acol4 + 1][arow] = av.y;
    As[acol4 + 2][arow] = av.z;
    As[acol4 + 3][arow] = av.w;
    *(float4*)&Bs[brow][bcol4] = bv;
    __syncthreads();
    #pragma unroll
    for (int k = 0; k < GBK; ++k) {
      float a[8], b[8];
      *(float4*)&a[0] = *(const float4*)&As[k][ty * 8 + 0];
      *(float4*)&a[4] = *(const float4*)&As[k][ty * 8 + 4];
      *(float4*)&b[0] = *(const float4*)&Bs[k][tx * 8 + 0];
      *(float4*)&b[4] = *(const float4*)&Bs[k][tx * 8 + 4];
      #pragma unroll
      for (int i = 0; i < 8; ++i)
        #pragma unroll
        for (int j = 0; j < 8; ++j)
          acc[i][j] = fmaf(a[i], b[j], acc[i][j]);
    }
  }

  #pragma unroll
  for (int i = 0; i < 8; ++i) {
    size_t r = (size_t)(row0 + ty * 8 + i);
    #pragma unroll
    for (int j = 0; j < 8; ++j) {
      int c = col0 + tx * 8 + j;
      float v = acc[i][j] + bias[c];
      if (relu) v = fmaxf(v, 0.0f);
      C[r * N + c] = v;
    }
  }
}

// ---------------------------------------------------------------------------
// out[r, :] = h2[r, :] @ W3[256,3] + b3 + res[r, :]   (wave per row)
// ---------------------------------------------------------------------------
__global__ __launch_bounds__(256) void final_kernel(
    const float* __restrict__ h2, const float* __restrict__ W3,
    const float* __restrict__ b3, const float* __restrict__ res,
    float* __restrict__ out, int M)
{
  __shared__ float sW3[768];
  const int tid = threadIdx.x;
  for (int i = tid; i < 768; i += 256) sW3[i] = W3[i];
  __syncthreads();

  const int wave = tid >> 6, lane = tid & 63;
  const int r = blockIdx.x * 4 + wave;
  if (r >= M) return;

  float4 h = ((const float4*)h2)[(size_t)r * 64 + lane];
  const int c = lane * 4;
  float a0 = h.x * sW3[(c + 0) * 3 + 0] + h.y * sW3[(c + 1) * 3 + 0]
           + h.z * sW3[(c + 2) * 3 + 0] + h.w * sW3[(c + 3) * 3 + 0];
  float a1 = h.x * sW3[(c + 0) * 3 + 1] + h.y * sW3[(c + 1) * 3 + 1]
           + h.z * sW3[(c + 2) * 3 + 1] + h.w * sW3[(c + 3) * 3 + 1];
  float a2 = h.x * sW3[(c + 0) * 3 + 2] + h.y * sW3[(c + 1) * 3 + 2]
           + h.z * sW3[(c + 2) * 3 + 2] + h.w * sW3[(c + 3) * 3 + 2];

  #pragma unroll
  for (int off = 32; off; off >>= 1) {
    a0 += __shfl_xor(a0, off);
    a1 += __shfl_xor(a1, off);
    a2 += __shfl_xor(a2, off);
  }
  if (lane == 0) {
    out[(size_t)r * 3 + 0] = a0 + b3[0] + res[(size_t)r * 3 + 0];
    out[(size_t)r * 3 + 1] = a1 + b3[1] + res[(size_t)r * 3 + 1];
    out[(size_t)r * 3 + 2] = a2 + b3[2] + res[(size_t)r * 3 + 2];
  }
}

// ---------------------------------------------------------------------------
extern "C" void kernel_launch(void* const* d_in, const int* in_sizes, int n_in,
                              void* d_out, int out_size, void* d_ws, size_t ws_size,
                              hipStream_t stream) {
  (void)in_sizes; (void)n_in; (void)out_size; (void)ws_size;
  const float* emb1   = (const float*)d_in[0];
  const float* l_y1   = (const float*)d_in[1];
  const float* l_pos1 = (const float*)d_in[2];
  const float* h_pos1 = (const float*)d_in[3];
  const float* emb2   = (const float*)d_in[4];
  const float* l_y2   = (const float*)d_in[5];
  const float* l_pos2 = (const float*)d_in[6];
  const float* h_pos2 = (const float*)d_in[7];
  const float* W1     = (const float*)d_in[8];
  const float* b1     = (const float*)d_in[9];
  const float* W2     = (const float*)d_in[10];
  const float* b2     = (const float*)d_in[11];
  const float* W3     = (const float*)d_in[12];
  const float* b3     = (const float*)d_in[13];
  float* out = (float*)d_out;

  const int Nh = 16384, Nl = 4096, H = 256;
  const size_t MB = 1024 * 1024;

  // workspace layout (aliasing is deliberate; stream is sequential):
  //   [0]        idxA   192KB
  //   [192K]     wA     192KB
  //   [384K]     tbuf   16MB   <- also partd_big (6.29MB) before build_t
  //   [384K+16M] h1     16MB   <- also parti_big; later partd2/parti2
  //   [384K+32M] diff   48KB
  //   [+48K]     res    192KB
  //   [+]        partdS 1.57MB, partiS 1.57MB (small 4096x4096 knn)
  char* ws = (char*)d_ws;
  int*   idxA   = (int*)(ws + 0);
  float* wA     = (float*)(ws + 196608);
  float* tbuf   = (float*)(ws + 393216);
  float* h1     = (float*)(ws + 393216 + 16 * MB);
  float* h2     = tbuf;                                  // reuse t region
  float* diff   = (float*)(ws + 393216 + 32 * MB);
  float* res    = (float*)(ws + 393216 + 32 * MB + 49152);
  float* partdS = (float*)(ws + 393216 + 32 * MB + 49152 + 196608);
  int*   partiS = (int*)  (ws + 393216 + 32 * MB + 49152 + 196608 + 1572864);

  float* partd_big = tbuf;             // dead before build_t writes tbuf
  int*   parti_big = (int*)h1;         // dead before gemm1 writes h1
  float* partd2    = h1;               // h1 dead after gemm2
  int*   parti2    = (int*)((char*)h1 + 8 * MB);

  // ---- branch 1: x = mlp(emb1 - interp(emb2; h_pos2 -> h_pos1)) ----
  // 16384x16384, chunk 512 -> 32 chunks, 2048 blocks (8/CU, full occupancy)
  knn_part_kernel<<<dim3(Nh / 256, 32), 256, 0, stream>>>(
      h_pos1, Nh, h_pos2, Nh, 512, partd_big, parti_big);
  knn_merge_kernel<<<dim3(Nh / 256), 256, 0, stream>>>(
      Nh, 32, partd_big, parti_big, 0, nullptr, nullptr, wA, idxA, nullptr);
  build_t_kernel<<<dim3(Nh * 64 / 256), 256, 0, stream>>>(
      emb1, emb2, wA, idxA, tbuf, Nh);
  gemm_bias_act_kernel<<<dim3(Nh / GBM, H / GBN), 256, 0, stream>>>(
      tbuf, W1, b1, h1, Nh, H, H, 1);
  gemm_bias_act_kernel<<<dim3(Nh / GBM, H / GBN), 256, 0, stream>>>(
      h1, W2, b2, h2, Nh, H, H, 1);

  // ---- branch 2: res = interp(l_y1 - interp(l_y2; l_pos2->l_pos1); l_pos1->h_pos1) ----
  // 4096x4096, chunk 128 -> 32 chunks, 512 blocks
  knn_part_kernel<<<dim3(Nl / 256, 32), 256, 0, stream>>>(
      l_pos1, Nl, l_pos2, Nl, 128, partdS, partiS);
  knn_merge_kernel<<<dim3(Nl / 256), 256, 0, stream>>>(
      Nl, 32, partdS, partiS, 1, l_y1, l_y2, nullptr, nullptr, diff);
  // 16384x4096, chunk 128 -> 32 chunks, 2048 blocks (partials alias h1)
  knn_part_kernel<<<dim3(Nh / 256, 32), 256, 0, stream>>>(
      h_pos1, Nh, l_pos1, Nl, 128, partd2, parti2);
  knn_merge_kernel<<<dim3(Nh / 256), 256, 0, stream>>>(
      Nh, 32, partd2, parti2, 2, nullptr, diff, nullptr, nullptr, res);

  // ---- final: out = (h2 @ W3 + b3) + res ----
  final_kernel<<<dim3(Nh / 4), 256, 0, stream>>>(h2, W3, b3, res, out, Nh);
}